// Round 2
// baseline (279.333 us; speedup 1.0000x reference)
//
#include <hip/hip_runtime.h>

// Problem constants (MultiHeadAttention_9397388443950)
#define B_   2
#define S_   1024
#define SP_  1024
#define L_   2048      // SP + S
#define E_   2048
#define H_   16
#define HD_  128
#define N3_  6144      // 3*E
#define M_   2048      // B*S
#define SCALE_ 0.08838834764831845f   // 1/sqrt(128)

typedef _Float16 f16x8 __attribute__((ext_vector_type(8)));
typedef _Float16 f16x4 __attribute__((ext_vector_type(4)));
typedef float    f32x4 __attribute__((ext_vector_type(4)));

#define MFMA16(a,b,c) __builtin_amdgcn_mfma_f32_16x16x32_f16(a,b,c,0,0,0)

__device__ __forceinline__ void gload16(const void* g, void* l) {
  __builtin_amdgcn_global_load_lds(
      (const __attribute__((address_space(1))) void*)g,
      (__attribute__((address_space(3))) void*)l, 16, 0, 0);
}

// Conflict-free LDS granule layout for [R rows][32 f16] tiles (BK=32):
// granule(row,cg) = (row>>3)*32 + cg*8 + (row&7)   (cg = 16B-granule 0..3)
// Frag read bank = (row&7)*4 -> 2-way across r=0..15 (free, m136).
__device__ __forceinline__ int gstore(int row, int cg) {
  return ((row >> 3) << 5) + (cg << 3) + (row & 7);
}

// ---------------- f32 -> fp16 convert (8 elems/thread) ----------------
__global__ __launch_bounds__(256) void k_cvt(const float* __restrict__ in,
                                             _Float16* __restrict__ out, int n8) {
  int t = blockIdx.x * 256 + threadIdx.x;
  if (t >= n8) return;
  const float4* p = (const float4*)in + (size_t)t * 2;
  float4 a = p[0], b = p[1];
  f16x8 o;
  o[0]=(_Float16)a.x; o[1]=(_Float16)a.y; o[2]=(_Float16)a.z; o[3]=(_Float16)a.w;
  o[4]=(_Float16)b.x; o[5]=(_Float16)b.y; o[6]=(_Float16)b.z; o[7]=(_Float16)b.w;
  *((f16x8*)out + t) = o;
}

// ---------------- RoPE cos/sin table ----------------
__global__ __launch_bounds__(256) void k_cstab(float2* __restrict__ cs) {
  int t = blockIdx.x * 256 + threadIdx.x;     // 1024*128
  int pos = t >> 7, d = t & 127;
  float inv = exp2f(-(float)(d & 63) * (13.287712379549449f / 64.0f));
  float ang = (float)(SP_ + pos) * inv;
  float s, c;
  sincosf(ang, &s, &c);
  cs[t] = make_float2(c, s);
}

// ---------------- past_key -> Kc rows [0,SP) ----------------
__global__ __launch_bounds__(256) void k_pastk(const float* __restrict__ pk,
                                               _Float16* __restrict__ Kc) {
  int t = blockIdx.x * 256 + threadIdx.x;
  int d8 = t & 15; int rest = t >> 4;
  int pos = rest & 1023; rest >>= 10;
  int h = rest & 15; int b = rest >> 4;
  const float* src = pk + ((size_t)(b * SP_ + pos) * H_ + h) * HD_ + d8 * 8;
  float4 a = *(const float4*)src, c4 = *(const float4*)(src + 4);
  f16x8 o;
  o[0]=(_Float16)a.x;  o[1]=(_Float16)a.y;  o[2]=(_Float16)a.z;  o[3]=(_Float16)a.w;
  o[4]=(_Float16)c4.x; o[5]=(_Float16)c4.y; o[6]=(_Float16)c4.z; o[7]=(_Float16)c4.w;
  *(f16x8*)(Kc + ((size_t)(b * H_ + h) * L_ + pos) * HD_ + d8 * 8) = o;
}

// ---------------- past_value -> Vt (transpose) ----------------
__global__ __launch_bounds__(256) void k_pastv(const float* __restrict__ pv,
                                               _Float16* __restrict__ Vt) {
  __shared__ _Float16 tile[64][72];
  int bh = blockIdx.x; int b = bh >> 4, h = bh & 15;
  int p0 = blockIdx.y * 64, dd0 = blockIdx.z * 64;
  for (int e = threadIdx.x; e < 4096; e += 256) {
    int p = e >> 6, d = e & 63;
    tile[p][d] = (_Float16)pv[((size_t)(b * SP_ + p0 + p) * H_ + h) * HD_ + dd0 + d];
  }
  __syncthreads();
  for (int e = threadIdx.x; e < 4096; e += 256) {
    int d = e >> 6, p = e & 63;
    Vt[((size_t)bh * HD_ + dd0 + d) * L_ + p0 + p] = tile[p][d];
  }
}

// ---------------- new v -> Vt cols [SP,L) ----------------
__global__ __launch_bounds__(256) void k_newv(const _Float16* __restrict__ qkvh,
                                              _Float16* __restrict__ Vt) {
  __shared__ _Float16 tile[64][72];
  int bh = blockIdx.x; int b = bh >> 4, h = bh & 15;
  int i0 = blockIdx.y * 64, dd0 = blockIdx.z * 64;
  for (int e = threadIdx.x; e < 4096; e += 256) {
    int p = e >> 6, d = e & 63;
    tile[p][d] = qkvh[(size_t)(b * S_ + i0 + p) * N3_ + 2 * E_ + h * HD_ + dd0 + d];
  }
  __syncthreads();
  for (int e = threadIdx.x; e < 4096; e += 256) {
    int d = e >> 6, p = e & 63;
    Vt[((size_t)bh * HD_ + dd0 + d) * L_ + SP_ + i0 + p] = tile[p][d];
  }
}

// ---------------- RoPE q,k ----------------
__global__ __launch_bounds__(256) void k_rope(const _Float16* __restrict__ qkvh,
                                              const float2* __restrict__ cs,
                                              _Float16* __restrict__ Qh,
                                              _Float16* __restrict__ Kc) {
  int t = blockIdx.x * 256 + threadIdx.x;
  int m = t >> 10, pr = t & 1023;
  int h = pr >> 6, dp = pr & 63;
  int d0 = dp * 2;
  int b = m >> 10, i = m & 1023;
  const _Float16* qp = qkvh + (size_t)m * N3_ + h * HD_ + d0;
  float qe = (float)qp[0], qo = (float)qp[1];
  float ke = (float)qp[E_], ko = (float)qp[E_ + 1];
  float2 c0 = cs[i * HD_ + d0], c1 = cs[i * HD_ + d0 + 1];
  float q0v = qe * c0.x - qo * c0.y;
  float q1v = qo * c1.x + qe * c1.y;
  float k0v = ke * c0.x - ko * c0.y;
  float k1v = ko * c1.x + ke * c1.y;
  size_t qi = ((size_t)(b * H_ + h) * S_ + i) * HD_ + d0;
  Qh[qi]     = (_Float16)(q0v * SCALE_);
  Qh[qi + 1] = (_Float16)(q1v * SCALE_);
  size_t ki = ((size_t)(b * H_ + h) * L_ + SP_ + i) * HD_ + d0;
  Kc[ki]     = (_Float16)k0v;
  Kc[ki + 1] = (_Float16)k1v;
}

// ============ GEMM-256: 128(M)x256(N) tile, BK=32, 4 waves, 3-stage pipe ====
// Wave w owns 128x64 output (8 M-frags x 4 N-frags). Counted vmcnt (T4),
// raw s_barrier (no compiler vmcnt(0) drain), setprio (T5), swizzled LDS (T2),
// XCD-aware block swizzle (T1).
__device__ __forceinline__ void stage_tile(const _Float16* __restrict__ A,
                                           const _Float16* __restrict__ Bw,
                                           _Float16* sa, _Float16* sb,
                                           int m0, int n0, int K, int kt,
                                           int w, int lane) {
#pragma unroll
  for (int j = 0; j < 2; j++) {                 // A: 512 granules
    int gi = w * 128 + j * 64 + lane;
    int row = ((gi >> 5) << 3) + (gi & 7);
    int cg = (gi >> 3) & 3;
    gload16(A + (size_t)(m0 + row) * K + kt + cg * 8,
            sa + (size_t)(w * 128 + j * 64) * 8);
  }
#pragma unroll
  for (int j = 0; j < 4; j++) {                 // B: 1024 granules
    int gi = w * 256 + j * 64 + lane;
    int row = ((gi >> 5) << 3) + (gi & 7);
    int cg = (gi >> 3) & 3;
    gload16(Bw + (size_t)(n0 + row) * K + kt + cg * 8,
            sb + (size_t)(w * 256 + j * 64) * 8);
  }
}

__global__ __launch_bounds__(256, 2) void k_gemm256(const _Float16* __restrict__ A,
                                                    const _Float16* __restrict__ Bw,
                                                    _Float16* __restrict__ C,
                                                    int M, int N, int K) {
  __shared__ _Float16 SA[3][128 * 32];
  __shared__ _Float16 SB[3][256 * 32];
  const int tid = threadIdx.x, w = tid >> 6, lane = tid & 63;
  const int r = lane & 15, g = lane >> 4;
  // XCD-aware swizzle: 8 XCDs, nwg = gridDim.x*gridDim.y (multiple of 8 here)
  int nwg = gridDim.x * gridDim.y;
  int flat = blockIdx.y * gridDim.x + blockIdx.x;
  int cpx = nwg >> 3;
  int swz = (flat & 7) * cpx + (flat >> 3);
  const int m0 = (swz / gridDim.x) * 128, n0 = (swz % gridDim.x) * 256;

  _Float16 *a0 = SA[0], *a1 = SA[1], *a2 = SA[2];
  _Float16 *b0 = SB[0], *b1 = SB[1], *b2 = SB[2];
  const int NT = K >> 5;
  f32x4 acc[8][4] = {};

  // prologue: stage tiles 0,1 (6 gloads/wave each)
  stage_tile(A, Bw, a0, b0, m0, n0, K, 0, w, lane);
  stage_tile(A, Bw, a1, b1, m0, n0, K, 32, w, lane);

  for (int t = 0; t < NT; ++t) {
    if (t + 2 < NT)
      stage_tile(A, Bw, a2, b2, m0, n0, K, (t + 2) << 5, w, lane);
    // wait for tile t (my 6 loads of it are the oldest outstanding)
    if (t < NT - 2)       asm volatile("s_waitcnt vmcnt(12)" ::: "memory");
    else if (t == NT - 2) asm volatile("s_waitcnt vmcnt(6)" ::: "memory");
    else                  asm volatile("s_waitcnt vmcnt(0)" ::: "memory");
    __builtin_amdgcn_sched_barrier(0);
    __builtin_amdgcn_s_barrier();
    __builtin_amdgcn_sched_barrier(0);

    // fragments from buf0
    f16x8 bf[4], af[8];
#pragma unroll
    for (int nf = 0; nf < 4; nf++) {
      int row = w * 64 + nf * 16 + r;
      bf[nf] = *(const f16x8*)(b0 + ((size_t)gstore(row, g) << 3));
    }
#pragma unroll
    for (int mf = 0; mf < 8; mf++) {
      int row = mf * 16 + r;
      af[mf] = *(const f16x8*)(a0 + ((size_t)gstore(row, g) << 3));
    }
    __builtin_amdgcn_s_setprio(1);
#pragma unroll
    for (int mf = 0; mf < 8; mf++)
#pragma unroll
      for (int nf = 0; nf < 4; nf++)
        acc[mf][nf] = MFMA16(af[mf], bf[nf], acc[mf][nf]);
    __builtin_amdgcn_s_setprio(0);

    asm volatile("s_waitcnt lgkmcnt(0)" ::: "memory");
    __builtin_amdgcn_sched_barrier(0);
    __builtin_amdgcn_s_barrier();
    __builtin_amdgcn_sched_barrier(0);

    _Float16* ra = a0; a0 = a1; a1 = a2; a2 = ra;
    _Float16* rb = b0; b0 = b1; b1 = b2; b2 = rb;
  }

  // epilogue: C[m0+mf*16+g*4+q][n0+w*64+nf*16+r] (fp16 out)
#pragma unroll
  for (int mf = 0; mf < 8; mf++)
#pragma unroll
    for (int nf = 0; nf < 4; nf++)
#pragma unroll
      for (int q = 0; q < 4; q++) {
        size_t idx = (size_t)(m0 + mf * 16 + g * 4 + q) * N + n0 + w * 64 + nf * 16 + r;
        C[idx] = (_Float16)acc[mf][nf][q];
      }
}

// ---------------- GEMM (m97 structure, conflict-free LDS) — used for out-proj
template<bool F16OUT>
__global__ __launch_bounds__(256) void k_gemm(const _Float16* __restrict__ A,
                                              const _Float16* __restrict__ Bw,
                                              void* __restrict__ Cout,
                                              int M, int N, int K) {
  __shared__ _Float16 As[128 * 32];
  __shared__ _Float16 Bs[128 * 32];
  const int tid = threadIdx.x, w = tid >> 6, lane = tid & 63;
  const int r = lane & 15, g = lane >> 4;
  const int m0 = blockIdx.y * 128, n0 = blockIdx.x * 128;
  const int wm = (w >> 1) * 64, wn = (w & 1) * 64;
  f32x4 acc[4][4] = {};
  for (int kt = 0; kt < K; kt += 32) {
#pragma unroll
    for (int it = 0; it < 2; it++) {
      int bg = it * 256 + w * 64;
      int gi = bg + lane;
      int row = ((gi >> 5) << 3) + (gi & 7);
      int cg = (gi >> 3) & 3;
      gload16(A  + (size_t)(m0 + row) * K + kt + cg * 8, &As[bg * 8]);
      gload16(Bw + (size_t)(n0 + row) * K + kt + cg * 8, &Bs[bg * 8]);
    }
    __syncthreads();
    f16x8 af[4], bf[4];
#pragma unroll
    for (int i = 0; i < 4; i++) {
      af[i] = *(const f16x8*)&As[gstore(wm + i * 16 + r, g) * 8];
      bf[i] = *(const f16x8*)&Bs[gstore(wn + i * 16 + r, g) * 8];
    }
#pragma unroll
    for (int i = 0; i < 4; i++)
#pragma unroll
      for (int j = 0; j < 4; j++)
        acc[i][j] = MFMA16(af[i], bf[j], acc[i][j]);
    __syncthreads();
  }
#pragma unroll
  for (int i = 0; i < 4; i++)
#pragma unroll
    for (int j = 0; j < 4; j++)
#pragma unroll
      for (int q = 0; q < 4; q++) {
        size_t idx = (size_t)(m0 + wm + i * 16 + g * 4 + q) * N + n0 + wn + j * 16 + r;
        if constexpr (F16OUT) ((_Float16*)Cout)[idx] = (_Float16)acc[i][j][q];
        else                  ((float*)Cout)[idx]    = acc[i][j][q];
      }
}

// ---------------- Flash attention (unchanged from R1) ----------------
__global__ __launch_bounds__(256) void k_attn(const _Float16* __restrict__ Qh,
                                              const _Float16* __restrict__ Kc,
                                              const _Float16* __restrict__ Vt,
                                              _Float16* __restrict__ Oh) {
  __shared__ _Float16 Kl[64 * 128];
  __shared__ _Float16 Vl[128 * 64];
  __shared__ _Float16 Pl[4][16 * 64];
  const int tid = threadIdx.x, w = tid >> 6, lane = tid & 63;
  const int r = lane & 15, g = lane >> 4;
  const int bh = blockIdx.x, tile = blockIdx.y;
  const int i0 = tile * 64, q0 = i0 + w * 16;
  const _Float16* Kbase = Kc + (size_t)bh * L_ * HD_;
  const _Float16* Vbase = Vt + (size_t)bh * HD_ * L_;
  f16x8 qf[4];
  {
    const _Float16* qp = Qh + ((size_t)bh * S_ + q0 + r) * HD_ + g * 8;
#pragma unroll
    for (int kk = 0; kk < 4; kk++) qf[kk] = *(const f16x8*)(qp + kk * 32);
  }
  f32x4 acc[8] = {};
  float mrun = -1e30f, lrun = 0.f;
  const int lim = SP_ + q0 + r;
  const int nch = (SP_ + i0 + 64) >> 6;
  for (int c = 0; c < nch; c++) {
    const int c0 = c << 6;
#pragma unroll
    for (int it = 0; it < 4; it++) {
      int bg = it * 256 + w * 64;
      int gr = bg + lane;
      int krow = gr >> 4, kc = ((gr & 15) ^ (krow & 7)) * 8;
      gload16(Kbase + (size_t)(c0 + krow) * HD_ + kc, &Kl[bg * 8]);
      int vrow = gr >> 3, vc = ((gr & 7) ^ (vrow & 7)) * 8;
      gload16(Vbase + (size_t)vrow * L_ + c0 + vc, &Vl[bg * 8]);
    }
    __syncthreads();
    f32x4 sc[4] = {};
#pragma unroll
    for (int mf = 0; mf < 4; mf++)
#pragma unroll
      for (int kk = 0; kk < 4; kk++) {
        int row = mf * 16 + r;
        int gran = (g + kk * 4) ^ (row & 7);
        f16x8 kf = *(const f16x8*)&Kl[row * 128 + gran * 8];
        sc[mf] = MFMA16(kf, qf[kk], sc[mf]);
      }
    float p[4][4];
    float rmax = -1e30f;
#pragma unroll
    for (int mf = 0; mf < 4; mf++)
#pragma unroll
      for (int jj = 0; jj < 4; jj++) {
        float v = sc[mf][jj];
        int kp = c0 + mf * 16 + g * 4 + jj;
        if (kp > lim) v = -1e30f;
        p[mf][jj] = v;
        rmax = fmaxf(rmax, v);
      }
    rmax = fmaxf(rmax, __shfl_xor(rmax, 16));
    rmax = fmaxf(rmax, __shfl_xor(rmax, 32));
    float mnew = fmaxf(mrun, rmax);
    float scale = __expf(mrun - mnew);
    float psum = 0.f;
#pragma unroll
    for (int mf = 0; mf < 4; mf++)
#pragma unroll
      for (int jj = 0; jj < 4; jj++) {
        float e = __expf(p[mf][jj] - mnew);
        p[mf][jj] = e;
        psum += e;
      }
    psum += __shfl_xor(psum, 16);
    psum += __shfl_xor(psum, 32);
    lrun = lrun * scale + psum;
    mrun = mnew;
#pragma unroll
    for (int mf = 0; mf < 4; mf++) {
      f16x4 ph;
#pragma unroll
      for (int jj = 0; jj < 4; jj++) ph[jj] = (_Float16)p[mf][jj];
      int g16 = (mf * 2 + (g >> 1)) ^ (r & 7);
      *(f16x4*)&Pl[w][r * 64 + g16 * 8 + (g & 1) * 4] = ph;
    }
    float scj[4];
#pragma unroll
    for (int jj = 0; jj < 4; jj++) scj[jj] = __shfl(scale, g * 4 + jj);
#pragma unroll
    for (int nf = 0; nf < 8; nf++)
#pragma unroll
      for (int jj = 0; jj < 4; jj++) acc[nf][jj] *= scj[jj];
#pragma unroll
    for (int kk = 0; kk < 2; kk++) {
      f16x8 pf = *(const f16x8*)&Pl[w][r * 64 + ((g + kk * 4) ^ (r & 7)) * 8];
#pragma unroll
      for (int nf = 0; nf < 8; nf++) {
        int vrow = nf * 16 + r;
        int gran = (g + kk * 4) ^ (vrow & 7);
        f16x8 vf = *(const f16x8*)&Vl[vrow * 64 + gran * 8];
        acc[nf] = MFMA16(pf, vf, acc[nf]);
      }
    }
    __syncthreads();
  }
  float inv[4];
#pragma unroll
  for (int jj = 0; jj < 4; jj++) inv[jj] = 1.f / __shfl(lrun, g * 4 + jj);
  const int b = bh >> 4, h = bh & 15;
#pragma unroll
  for (int nf = 0; nf < 8; nf++)
#pragma unroll
    for (int jj = 0; jj < 4; jj++) {
      size_t idx = (size_t)(b * S_ + i0 + w * 16 + g * 4 + jj) * E_ + h * HD_ + nf * 16 + r;
      Oh[idx] = (_Float16)(acc[nf][jj] * inv[jj]);
    }
}

extern "C" void kernel_launch(void* const* d_in, const int* in_sizes, int n_in,
                              void* d_out, int out_size, void* d_ws, size_t ws_size,
                              hipStream_t stream) {
  (void)in_sizes; (void)n_in; (void)out_size; (void)ws_size;
  const float* x    = (const float*)d_in[0];
  const float* Wqkv = (const float*)d_in[1];
  const float* Wout = (const float*)d_in[2];
  const float* pk   = (const float*)d_in[3];
  const float* pv   = (const float*)d_in[4];

  char* ws = (char*)d_ws;
  _Float16* Xh   = (_Float16*)(ws);               // 8.39MB  (reused as Oh)
  _Float16* Wh   = (_Float16*)(ws + 8388608);     // 25.2MB  (reused as Woh)
  _Float16* qkvh = (_Float16*)(ws + 33554432);    // 25.2MB
  _Float16* Qhb  = (_Float16*)(ws + 58720256);    // 8.39MB
  _Float16* Kcb  = (_Float16*)(ws + 67108864);    // 16.8MB
  _Float16* Vtb  = (_Float16*)(ws + 83886080);    // 16.8MB
  float2*   cs   = (float2*)  (ws + 100663296);   // 1MB
  _Float16* Ohb  = Xh;
  _Float16* Woh  = Wh;

  k_cvt  <<<2048, 256, 0, stream>>>(x, Xh, 524288);
  k_cvt  <<<6144, 256, 0, stream>>>(Wqkv, Wh, 1572864);
  k_cstab<<<512,  256, 0, stream>>>(cs);
  k_pastk<<<2048, 256, 0, stream>>>(pk, Kcb);
  k_pastv<<<dim3(32, 16, 2), 256, 0, stream>>>(pv, Vtb);
  k_gemm256<<<dim3(24, 16), 256, 0, stream>>>(Xh, Wh, qkvh, M_, N3_, E_);
  k_cvt  <<<2048, 256, 0, stream>>>(Wout, Woh, 524288);
  k_rope <<<8192, 256, 0, stream>>>(qkvh, cs, Qhb, Kcb);
  k_newv <<<dim3(32, 16, 2), 256, 0, stream>>>(qkvh, Vtb);
  k_attn <<<dim3(32, 16), 256, 0, stream>>>(Qhb, Kcb, Vtb, Ohb);
  k_gemm<false><<<dim3(16, 16), 256, 0, stream>>>(Ohb, Woh, d_out, M_, E_, E_);
}

// Round 3
// 253.002 us; speedup vs baseline: 1.1041x; 1.1041x over previous
//
#include <hip/hip_runtime.h>

// Problem constants (MultiHeadAttention_9397388443950)
#define B_   2
#define S_   1024
#define SP_  1024
#define L_   2048      // SP + S
#define E_   2048
#define H_   16
#define HD_  128
#define N3_  6144      // 3*E
#define M_   2048      // B*S
#define SCALE_ 0.08838834764831845f   // 1/sqrt(128)

typedef _Float16 f16x8 __attribute__((ext_vector_type(8)));
typedef _Float16 f16x4 __attribute__((ext_vector_type(4)));
typedef float    f32x4 __attribute__((ext_vector_type(4)));

#define MFMA16(a,b,c) __builtin_amdgcn_mfma_f32_16x16x32_f16(a,b,c,0,0,0)

__device__ __forceinline__ void gload16(const void* g, void* l) {
  __builtin_amdgcn_global_load_lds(
      (const __attribute__((address_space(1))) void*)g,
      (__attribute__((address_space(3))) void*)l, 16, 0, 0);
}

#define SBAR0 __builtin_amdgcn_sched_barrier(0)
#define BARRIER do { SBAR0; __builtin_amdgcn_s_barrier(); SBAR0; } while (0)

// Conflict-free LDS granule layout for [R rows][32 f16] tiles:
// granule(row,cg) = (row>>3)*32 + cg*8 + (row&7)
__device__ __forceinline__ int gstore(int row, int cg) {
  return ((row >> 3) << 5) + (cg << 3) + (row & 7);
}

// ---------------- f32 -> fp16 convert (8 elems/thread) ----------------
__global__ __launch_bounds__(256) void k_cvt(const float* __restrict__ in,
                                             _Float16* __restrict__ out, int n8) {
  int t = blockIdx.x * 256 + threadIdx.x;
  if (t >= n8) return;
  const float4* p = (const float4*)in + (size_t)t * 2;
  float4 a = p[0], b = p[1];
  f16x8 o;
  o[0]=(_Float16)a.x; o[1]=(_Float16)a.y; o[2]=(_Float16)a.z; o[3]=(_Float16)a.w;
  o[4]=(_Float16)b.x; o[5]=(_Float16)b.y; o[6]=(_Float16)b.z; o[7]=(_Float16)b.w;
  *((f16x8*)out + t) = o;
}

// ---------------- RoPE cos/sin table ----------------
__global__ __launch_bounds__(256) void k_cstab(float2* __restrict__ cs) {
  int t = blockIdx.x * 256 + threadIdx.x;     // 1024*128
  int pos = t >> 7, d = t & 127;
  float inv = exp2f(-(float)(d & 63) * (13.287712379549449f / 64.0f));
  float ang = (float)(SP_ + pos) * inv;
  float s, c;
  sincosf(ang, &s, &c);
  cs[t] = make_float2(c, s);
}

// ---------------- past_key -> Kc rows [0,SP) ----------------
__global__ __launch_bounds__(256) void k_pastk(const float* __restrict__ pk,
                                               _Float16* __restrict__ Kc) {
  int t = blockIdx.x * 256 + threadIdx.x;
  int d8 = t & 15; int rest = t >> 4;
  int pos = rest & 1023; rest >>= 10;
  int h = rest & 15; int b = rest >> 4;
  const float* src = pk + ((size_t)(b * SP_ + pos) * H_ + h) * HD_ + d8 * 8;
  float4 a = *(const float4*)src, c4 = *(const float4*)(src + 4);
  f16x8 o;
  o[0]=(_Float16)a.x;  o[1]=(_Float16)a.y;  o[2]=(_Float16)a.z;  o[3]=(_Float16)a.w;
  o[4]=(_Float16)c4.x; o[5]=(_Float16)c4.y; o[6]=(_Float16)c4.z; o[7]=(_Float16)c4.w;
  *(f16x8*)(Kc + ((size_t)(b * H_ + h) * L_ + pos) * HD_ + d8 * 8) = o;
}

// ---------------- past_value -> Vt (transpose) ----------------
__global__ __launch_bounds__(256) void k_pastv(const float* __restrict__ pv,
                                               _Float16* __restrict__ Vt) {
  __shared__ _Float16 tile[64][72];
  int bh = blockIdx.x; int b = bh >> 4, h = bh & 15;
  int p0 = blockIdx.y * 64, dd0 = blockIdx.z * 64;
  for (int e = threadIdx.x; e < 4096; e += 256) {
    int p = e >> 6, d = e & 63;
    tile[p][d] = (_Float16)pv[((size_t)(b * SP_ + p0 + p) * H_ + h) * HD_ + dd0 + d];
  }
  __syncthreads();
  for (int e = threadIdx.x; e < 4096; e += 256) {
    int d = e >> 6, p = e & 63;
    Vt[((size_t)bh * HD_ + dd0 + d) * L_ + p0 + p] = tile[p][d];
  }
}

// ---------------- new v -> Vt cols [SP,L) ----------------
__global__ __launch_bounds__(256) void k_newv(const _Float16* __restrict__ qkvh,
                                              _Float16* __restrict__ Vt) {
  __shared__ _Float16 tile[64][72];
  int bh = blockIdx.x; int b = bh >> 4, h = bh & 15;
  int i0 = blockIdx.y * 64, dd0 = blockIdx.z * 64;
  for (int e = threadIdx.x; e < 4096; e += 256) {
    int p = e >> 6, d = e & 63;
    tile[p][d] = qkvh[(size_t)(b * S_ + i0 + p) * N3_ + 2 * E_ + h * HD_ + dd0 + d];
  }
  __syncthreads();
  for (int e = threadIdx.x; e < 4096; e += 256) {
    int d = e >> 6, p = e & 63;
    Vt[((size_t)bh * HD_ + dd0 + d) * L_ + SP_ + i0 + p] = tile[p][d];
  }
}

// ---------------- RoPE q,k ----------------
__global__ __launch_bounds__(256) void k_rope(const _Float16* __restrict__ qkvh,
                                              const float2* __restrict__ cs,
                                              _Float16* __restrict__ Qh,
                                              _Float16* __restrict__ Kc) {
  int t = blockIdx.x * 256 + threadIdx.x;
  int m = t >> 10, pr = t & 1023;
  int h = pr >> 6, dp = pr & 63;
  int d0 = dp * 2;
  int b = m >> 10, i = m & 1023;
  const _Float16* qp = qkvh + (size_t)m * N3_ + h * HD_ + d0;
  float qe = (float)qp[0], qo = (float)qp[1];
  float ke = (float)qp[E_], ko = (float)qp[E_ + 1];
  float2 c0 = cs[i * HD_ + d0], c1 = cs[i * HD_ + d0 + 1];
  float q0v = qe * c0.x - qo * c0.y;
  float q1v = qo * c1.x + qe * c1.y;
  float k0v = ke * c0.x - ko * c0.y;
  float k1v = ko * c1.x + ke * c1.y;
  size_t qi = ((size_t)(b * H_ + h) * S_ + i) * HD_ + d0;
  Qh[qi]     = (_Float16)(q0v * SCALE_);
  Qh[qi + 1] = (_Float16)(q1v * SCALE_);
  size_t ki = ((size_t)(b * H_ + h) * L_ + SP_ + i) * HD_ + d0;
  Kc[ki]     = (_Float16)k0v;
  Kc[ki + 1] = (_Float16)k1v;
}

// ============ GEMM-8phase: 256x256 tile, BK=64, 8 waves, m201-style =========
// Half-tiles split along K: A_k0,B_k0,A_k1,B_k1 each 256rows x 32cols = 16KB.
// LDS ring: LA[4]/LB[4] half-slots (2 dbuf x 2 kk). Stage order per tile
// (A_k0,B_k0,A_k1,B_k1); last-read phases (1,2,3,4); slot (T,X) overwritten
// at rel phase X+2 >= lastread+1 -> race-free (barrier between).
// vmcnt(6) once per K-tile (3 half-tiles in flight). Swizzle: granule
// gi = row*4 + (cg ^ ((row>>1)&3)) -> 8 consecutive lanes hit 8 bank-groups.
__global__ __launch_bounds__(512, 2) void k_gemm8(const _Float16* __restrict__ A,
                                                  const _Float16* __restrict__ Bw,
                                                  _Float16* __restrict__ C,
                                                  int Mdim, int Ndim, int K, int nbn) {
  __shared__ _Float16 LA[4][8192];
  __shared__ _Float16 LB[4][8192];
  const int tid = threadIdx.x, w = tid >> 6, lane = tid & 63;
  const int r = lane & 15, g = lane >> 4;
  const int wr = w >> 2, wc = w & 3;
  const int xg = g ^ ((r >> 1) & 3);
  // XCD-aware swizzle (nwg = 192, divisible by 8)
  const int nwg = gridDim.x, flat = blockIdx.x, cpx = nwg >> 3;
  const int swz = (flat & 7) * cpx + (flat >> 3);
  const int m0 = (swz / nbn) * 256, n0 = (swz % nbn) * 256;
  const int NT = K >> 6;

  // stage half-tile hidx: tile=hidx>>2, kind: 0=A_k0,1=B_k0,2=A_k1,3=B_k1
  auto stage = [&](int hidx) {
    if (hidx >= 4 * NT) return;
    int Ts = hidx >> 2, kind = hidx & 3;
    int kk = kind >> 1, isB = kind & 1;
    const _Float16* src = isB ? Bw : A;
    int rb = isB ? n0 : m0;
    _Float16* slot = isB ? LB[(Ts & 1) * 2 + kk] : LA[(Ts & 1) * 2 + kk];
    int kt = (Ts << 6) + (kk << 5);
#pragma unroll
    for (int j = 0; j < 2; j++) {
      int chunk = j * 8 + w;
      int gi = chunk * 64 + lane;
      int row = gi >> 2;
      int cg = (gi & 3) ^ ((gi >> 3) & 3);
      gload16(src + (size_t)(rb + row) * K + kt + cg * 8,
              slot + (size_t)chunk * 512);
    }
  };

  f32x4 acc[8][4] = {};
  f16x8 af[8], bf0, bf1;

  // prologue: halves 0..6 (tile0 complete + tile1 A_k0,B_k0,A_k1)
#pragma unroll
  for (int h = 0; h < 7; h++) stage(h);
  asm volatile("s_waitcnt vmcnt(6)" ::: "memory");
  BARRIER;

  for (int T = 0; T < NT; ++T) {
    const int d = (T & 1) * 2;
    const _Float16* la0 = LA[d];
    const _Float16* lb0 = LB[d];
    const _Float16* la1 = LA[d + 1];
    const _Float16* lb1 = LB[d + 1];
    // ---- phase 1: A kk0 (8 reads) + B nf0,nf1 kk0; MFMA mf x {nf0,nf1} ----
#pragma unroll
    for (int mf = 0; mf < 8; mf++)
      af[mf] = *(const f16x8*)(la0 + (wr * 128 + mf * 16 + r) * 32 + xg * 8);
    bf0 = *(const f16x8*)(lb0 + (wc * 64 + r) * 32 + xg * 8);
    bf1 = *(const f16x8*)(lb0 + (wc * 64 + 16 + r) * 32 + xg * 8);
    stage(4 * T + 7);
    BARRIER;
    __builtin_amdgcn_s_setprio(1);
#pragma unroll
    for (int mf = 0; mf < 8; mf++) acc[mf][0] = MFMA16(af[mf], bf0, acc[mf][0]);
#pragma unroll
    for (int mf = 0; mf < 8; mf++) acc[mf][1] = MFMA16(af[mf], bf1, acc[mf][1]);
    __builtin_amdgcn_s_setprio(0);
    BARRIER;
    // ---- phase 2: B nf2,nf3 kk0; MFMA mf x {nf2,nf3} ----
    bf0 = *(const f16x8*)(lb0 + (wc * 64 + 32 + r) * 32 + xg * 8);
    bf1 = *(const f16x8*)(lb0 + (wc * 64 + 48 + r) * 32 + xg * 8);
    stage(4 * T + 8);
    BARRIER;
    __builtin_amdgcn_s_setprio(1);
#pragma unroll
    for (int mf = 0; mf < 8; mf++) acc[mf][2] = MFMA16(af[mf], bf0, acc[mf][2]);
#pragma unroll
    for (int mf = 0; mf < 8; mf++) acc[mf][3] = MFMA16(af[mf], bf1, acc[mf][3]);
    __builtin_amdgcn_s_setprio(0);
    BARRIER;
    // ---- phase 3: A kk1 (8) + B nf0,nf1 kk1 ----
#pragma unroll
    for (int mf = 0; mf < 8; mf++)
      af[mf] = *(const f16x8*)(la1 + (wr * 128 + mf * 16 + r) * 32 + xg * 8);
    bf0 = *(const f16x8*)(lb1 + (wc * 64 + r) * 32 + xg * 8);
    bf1 = *(const f16x8*)(lb1 + (wc * 64 + 16 + r) * 32 + xg * 8);
    stage(4 * T + 9);
    BARRIER;
    __builtin_amdgcn_s_setprio(1);
#pragma unroll
    for (int mf = 0; mf < 8; mf++) acc[mf][0] = MFMA16(af[mf], bf0, acc[mf][0]);
#pragma unroll
    for (int mf = 0; mf < 8; mf++) acc[mf][1] = MFMA16(af[mf], bf1, acc[mf][1]);
    __builtin_amdgcn_s_setprio(0);
    BARRIER;
    // ---- phase 4: B nf2,nf3 kk1; vmcnt; MFMA ----
    bf0 = *(const f16x8*)(lb1 + (wc * 64 + 32 + r) * 32 + xg * 8);
    bf1 = *(const f16x8*)(lb1 + (wc * 64 + 48 + r) * 32 + xg * 8);
    stage(4 * T + 10);
    BARRIER;
    __builtin_amdgcn_s_setprio(1);
#pragma unroll
    for (int mf = 0; mf < 8; mf++) acc[mf][2] = MFMA16(af[mf], bf0, acc[mf][2]);
#pragma unroll
    for (int mf = 0; mf < 8; mf++) acc[mf][3] = MFMA16(af[mf], bf1, acc[mf][3]);
    __builtin_amdgcn_s_setprio(0);
    if (T < NT - 2) asm volatile("s_waitcnt vmcnt(6)" ::: "memory");
    else            asm volatile("s_waitcnt vmcnt(0)" ::: "memory");
    BARRIER;
  }

  // epilogue: C[m0+wr*128+mf*16+g*4+q][n0+wc*64+nf*16+r]
#pragma unroll
  for (int mf = 0; mf < 8; mf++)
#pragma unroll
    for (int nf = 0; nf < 4; nf++)
#pragma unroll
      for (int q = 0; q < 4; q++) {
        size_t idx = (size_t)(m0 + wr * 128 + mf * 16 + g * 4 + q) * Ndim
                   + n0 + wc * 64 + nf * 16 + r;
        C[idx] = (_Float16)acc[mf][nf][q];
      }
}

// ---------------- GEMM (m97 structure, conflict-free LDS) — out-proj --------
template<bool F16OUT>
__global__ __launch_bounds__(256) void k_gemm(const _Float16* __restrict__ A,
                                              const _Float16* __restrict__ Bw,
                                              void* __restrict__ Cout,
                                              int M, int N, int K) {
  __shared__ _Float16 As[128 * 32];
  __shared__ _Float16 Bs[128 * 32];
  const int tid = threadIdx.x, w = tid >> 6, lane = tid & 63;
  const int r = lane & 15, g = lane >> 4;
  const int m0 = blockIdx.y * 128, n0 = blockIdx.x * 128;
  const int wm = (w >> 1) * 64, wn = (w & 1) * 64;
  f32x4 acc[4][4] = {};
  for (int kt = 0; kt < K; kt += 32) {
#pragma unroll
    for (int it = 0; it < 2; it++) {
      int bg = it * 256 + w * 64;
      int gi = bg + lane;
      int row = ((gi >> 5) << 3) + (gi & 7);
      int cg = (gi >> 3) & 3;
      gload16(A  + (size_t)(m0 + row) * K + kt + cg * 8, &As[bg * 8]);
      gload16(Bw + (size_t)(n0 + row) * K + kt + cg * 8, &Bs[bg * 8]);
    }
    __syncthreads();
    f16x8 af[4], bf[4];
#pragma unroll
    for (int i = 0; i < 4; i++) {
      af[i] = *(const f16x8*)&As[gstore(wm + i * 16 + r, g) * 8];
      bf[i] = *(const f16x8*)&Bs[gstore(wn + i * 16 + r, g) * 8];
    }
#pragma unroll
    for (int i = 0; i < 4; i++)
#pragma unroll
      for (int j = 0; j < 4; j++)
        acc[i][j] = MFMA16(af[i], bf[j], acc[i][j]);
    __syncthreads();
  }
#pragma unroll
  for (int i = 0; i < 4; i++)
#pragma unroll
    for (int j = 0; j < 4; j++)
#pragma unroll
      for (int q = 0; q < 4; q++) {
        size_t idx = (size_t)(m0 + wm + i * 16 + g * 4 + q) * N + n0 + wn + j * 16 + r;
        if constexpr (F16OUT) ((_Float16*)Cout)[idx] = (_Float16)acc[i][j][q];
        else                  ((float*)Cout)[idx]    = acc[i][j][q];
      }
}

// ---------------- Flash attention (unchanged) ----------------
__global__ __launch_bounds__(256) void k_attn(const _Float16* __restrict__ Qh,
                                              const _Float16* __restrict__ Kc,
                                              const _Float16* __restrict__ Vt,
                                              _Float16* __restrict__ Oh) {
  __shared__ _Float16 Kl[64 * 128];
  __shared__ _Float16 Vl[128 * 64];
  __shared__ _Float16 Pl[4][16 * 64];
  const int tid = threadIdx.x, w = tid >> 6, lane = tid & 63;
  const int r = lane & 15, g = lane >> 4;
  const int bh = blockIdx.x, tile = blockIdx.y;
  const int i0 = tile * 64, q0 = i0 + w * 16;
  const _Float16* Kbase = Kc + (size_t)bh * L_ * HD_;
  const _Float16* Vbase = Vt + (size_t)bh * HD_ * L_;
  f16x8 qf[4];
  {
    const _Float16* qp = Qh + ((size_t)bh * S_ + q0 + r) * HD_ + g * 8;
#pragma unroll
    for (int kk = 0; kk < 4; kk++) qf[kk] = *(const f16x8*)(qp + kk * 32);
  }
  f32x4 acc[8] = {};
  float mrun = -1e30f, lrun = 0.f;
  const int lim = SP_ + q0 + r;
  const int nch = (SP_ + i0 + 64) >> 6;
  for (int c = 0; c < nch; c++) {
    const int c0 = c << 6;
#pragma unroll
    for (int it = 0; it < 4; it++) {
      int bg = it * 256 + w * 64;
      int gr = bg + lane;
      int krow = gr >> 4, kc = ((gr & 15) ^ (krow & 7)) * 8;
      gload16(Kbase + (size_t)(c0 + krow) * HD_ + kc, &Kl[bg * 8]);
      int vrow = gr >> 3, vc = ((gr & 7) ^ (vrow & 7)) * 8;
      gload16(Vbase + (size_t)vrow * L_ + c0 + vc, &Vl[bg * 8]);
    }
    __syncthreads();
    f32x4 sc[4] = {};
#pragma unroll
    for (int mf = 0; mf < 4; mf++)
#pragma unroll
      for (int kk = 0; kk < 4; kk++) {
        int row = mf * 16 + r;
        int gran = (g + kk * 4) ^ (row & 7);
        f16x8 kf = *(const f16x8*)&Kl[row * 128 + gran * 8];
        sc[mf] = MFMA16(kf, qf[kk], sc[mf]);
      }
    float p[4][4];
    float rmax = -1e30f;
#pragma unroll
    for (int mf = 0; mf < 4; mf++)
#pragma unroll
      for (int jj = 0; jj < 4; jj++) {
        float v = sc[mf][jj];
        int kp = c0 + mf * 16 + g * 4 + jj;
        if (kp > lim) v = -1e30f;
        p[mf][jj] = v;
        rmax = fmaxf(rmax, v);
      }
    rmax = fmaxf(rmax, __shfl_xor(rmax, 16));
    rmax = fmaxf(rmax, __shfl_xor(rmax, 32));
    float mnew = fmaxf(mrun, rmax);
    float scale = __expf(mrun - mnew);
    float psum = 0.f;
#pragma unroll
    for (int mf = 0; mf < 4; mf++)
#pragma unroll
      for (int jj = 0; jj < 4; jj++) {
        float e = __expf(p[mf][jj] - mnew);
        p[mf][jj] = e;
        psum += e;
      }
    psum += __shfl_xor(psum, 16);
    psum += __shfl_xor(psum, 32);
    lrun = lrun * scale + psum;
    mrun = mnew;
#pragma unroll
    for (int mf = 0; mf < 4; mf++) {
      f16x4 ph;
#pragma unroll
      for (int jj = 0; jj < 4; jj++) ph[jj] = (_Float16)p[mf][jj];
      int g16 = (mf * 2 + (g >> 1)) ^ (r & 7);
      *(f16x4*)&Pl[w][r * 64 + g16 * 8 + (g & 1) * 4] = ph;
    }
    float scj[4];
#pragma unroll
    for (int jj = 0; jj < 4; jj++) scj[jj] = __shfl(scale, g * 4 + jj);
#pragma unroll
    for (int nf = 0; nf < 8; nf++)
#pragma unroll
      for (int jj = 0; jj < 4; jj++) acc[nf][jj] *= scj[jj];
#pragma unroll
    for (int kk = 0; kk < 2; kk++) {
      f16x8 pf = *(const f16x8*)&Pl[w][r * 64 + ((g + kk * 4) ^ (r & 7)) * 8];
#pragma unroll
      for (int nf = 0; nf < 8; nf++) {
        int vrow = nf * 16 + r;
        int gran = (g + kk * 4) ^ (vrow & 7);
        f16x8 vf = *(const f16x8*)&Vl[vrow * 64 + gran * 8];
        acc[nf] = MFMA16(pf, vf, acc[nf]);
      }
    }
    __syncthreads();
  }
  float inv[4];
#pragma unroll
  for (int jj = 0; jj < 4; jj++) inv[jj] = 1.f / __shfl(lrun, g * 4 + jj);
  const int b = bh >> 4, h = bh & 15;
#pragma unroll
  for (int nf = 0; nf < 8; nf++)
#pragma unroll
    for (int jj = 0; jj < 4; jj++) {
      size_t idx = (size_t)(b * S_ + i0 + w * 16 + g * 4 + jj) * E_ + h * HD_ + nf * 16 + r;
      Oh[idx] = (_Float16)(acc[nf][jj] * inv[jj]);
    }
}

extern "C" void kernel_launch(void* const* d_in, const int* in_sizes, int n_in,
                              void* d_out, int out_size, void* d_ws, size_t ws_size,
                              hipStream_t stream) {
  (void)in_sizes; (void)n_in; (void)out_size; (void)ws_size;
  const float* x    = (const float*)d_in[0];
  const float* Wqkv = (const float*)d_in[1];
  const float* Wout = (const float*)d_in[2];
  const float* pk   = (const float*)d_in[3];
  const float* pv   = (const float*)d_in[4];

  char* ws = (char*)d_ws;
  _Float16* Xh   = (_Float16*)(ws);               // 8.39MB  (reused as Oh)
  _Float16* Wh   = (_Float16*)(ws + 8388608);     // 25.2MB  (reused as Woh)
  _Float16* qkvh = (_Float16*)(ws + 33554432);    // 25.2MB
  _Float16* Qhb  = (_Float16*)(ws + 58720256);    // 8.39MB
  _Float16* Kcb  = (_Float16*)(ws + 67108864);    // 16.8MB
  _Float16* Vtb  = (_Float16*)(ws + 83886080);    // 16.8MB
  float2*   cs   = (float2*)  (ws + 100663296);   // 1MB
  _Float16* Ohb  = Xh;
  _Float16* Woh  = Wh;

  k_cvt  <<<2048, 256, 0, stream>>>(x, Xh, 524288);
  k_cvt  <<<6144, 256, 0, stream>>>(Wqkv, Wh, 1572864);
  k_cstab<<<512,  256, 0, stream>>>(cs);
  k_pastk<<<2048, 256, 0, stream>>>(pk, Kcb);
  k_pastv<<<dim3(32, 16, 2), 256, 0, stream>>>(pv, Vtb);
  k_gemm8<<<192, 512, 0, stream>>>(Xh, Wh, qkvh, M_, N3_, E_, 24);
  k_cvt  <<<2048, 256, 0, stream>>>(Wout, Woh, 524288);
  k_rope <<<8192, 256, 0, stream>>>(qkvh, cs, Qhb, Kcb);
  k_newv <<<dim3(32, 16, 2), 256, 0, stream>>>(qkvh, Vtb);
  k_attn <<<dim3(32, 16), 256, 0, stream>>>(Qhb, Kcb, Vtb, Ohb);
  k_gemm<false><<<dim3(16, 16), 256, 0, stream>>>(Ohb, Woh, d_out, M_, E_, E_);
}

// Round 4
// 241.018 us; speedup vs baseline: 1.1590x; 1.0497x over previous
//
#include <hip/hip_runtime.h>

// Problem constants (MultiHeadAttention_9397388443950)
#define B_   2
#define S_   1024
#define SP_  1024
#define L_   2048      // SP + S
#define E_   2048
#define H_   16
#define HD_  128
#define N3_  6144      // 3*E
#define M_   2048      // B*S
#define SCALE_ 0.08838834764831845f   // 1/sqrt(128)

typedef _Float16 f16x8 __attribute__((ext_vector_type(8)));
typedef _Float16 f16x4 __attribute__((ext_vector_type(4)));
typedef _Float16 f16x2 __attribute__((ext_vector_type(2)));
typedef float    f32x4 __attribute__((ext_vector_type(4)));

#define MFMA16(a,b,c) __builtin_amdgcn_mfma_f32_16x16x32_f16(a,b,c,0,0,0)

__device__ __forceinline__ void gload16(const void* g, void* l) {
  __builtin_amdgcn_global_load_lds(
      (const __attribute__((address_space(1))) void*)g,
      (__attribute__((address_space(3))) void*)l, 16, 0, 0);
}

#define SBAR0 __builtin_amdgcn_sched_barrier(0)
#define BARRIER do { SBAR0; __builtin_amdgcn_s_barrier(); SBAR0; } while (0)

// Conflict-free LDS granule layout for [R rows][32 f16] tiles:
// granule(row,cg) = (row>>3)*32 + cg*8 + (row&7)
__device__ __forceinline__ int gstore(int row, int cg) {
  return ((row >> 3) << 5) + (cg << 3) + (row & 7);
}

// ---------------- merged f32 -> fp16 convert: x, Wqkv, Wout ----------------
__global__ __launch_bounds__(256) void k_cvtall(const float* __restrict__ x,
                                                const float* __restrict__ wq,
                                                const float* __restrict__ wo,
                                                _Float16* __restrict__ xh,
                                                _Float16* __restrict__ wh,
                                                _Float16* __restrict__ woh) {
  int t = blockIdx.x * 256 + threadIdx.x;       // 2,621,440 granules total
  const float* src; _Float16* dst; int off;
  if (t < 524288)       { src = x;  dst = xh;  off = t; }
  else if (t < 2097152) { src = wq; dst = wh;  off = t - 524288; }
  else                  { src = wo; dst = woh; off = t - 2097152; }
  const float4* p = (const float4*)src + (size_t)off * 2;
  float4 a = p[0], b = p[1];
  f16x8 o;
  o[0]=(_Float16)a.x; o[1]=(_Float16)a.y; o[2]=(_Float16)a.z; o[3]=(_Float16)a.w;
  o[4]=(_Float16)b.x; o[5]=(_Float16)b.y; o[6]=(_Float16)b.z; o[7]=(_Float16)b.w;
  *((f16x8*)dst + off) = o;
}

// ---------------- RoPE cos/sin table: cs[i*128+d] for pos=SP+i -------------
__global__ __launch_bounds__(256) void k_cstab(float2* __restrict__ cs) {
  int t = blockIdx.x * 256 + threadIdx.x;     // 1024*128
  int pos = t >> 7, d = t & 127;
  float inv = exp2f(-(float)(d & 63) * (13.287712379549449f / 64.0f));
  float ang = (float)(SP_ + pos) * inv;
  float s, c;
  sincosf(ang, &s, &c);
  cs[t] = make_float2(c, s);
}

// ---------------- past_key -> Kc rows [0,SP) ----------------
__global__ __launch_bounds__(256) void k_pastk(const float* __restrict__ pk,
                                               _Float16* __restrict__ Kc) {
  int t = blockIdx.x * 256 + threadIdx.x;
  int d8 = t & 15; int rest = t >> 4;
  int pos = rest & 1023; rest >>= 10;
  int h = rest & 15; int b = rest >> 4;
  const float* src = pk + ((size_t)(b * SP_ + pos) * H_ + h) * HD_ + d8 * 8;
  float4 a = *(const float4*)src, c4 = *(const float4*)(src + 4);
  f16x8 o;
  o[0]=(_Float16)a.x;  o[1]=(_Float16)a.y;  o[2]=(_Float16)a.z;  o[3]=(_Float16)a.w;
  o[4]=(_Float16)c4.x; o[5]=(_Float16)c4.y; o[6]=(_Float16)c4.z; o[7]=(_Float16)c4.w;
  *(f16x8*)(Kc + ((size_t)(b * H_ + h) * L_ + pos) * HD_ + d8 * 8) = o;
}

// ---------------- past_value -> Vt (transpose) ----------------
__global__ __launch_bounds__(256) void k_pastv(const float* __restrict__ pv,
                                               _Float16* __restrict__ Vt) {
  __shared__ _Float16 tile[64][72];
  int bh = blockIdx.x; int b = bh >> 4, h = bh & 15;
  int p0 = blockIdx.y * 64, dd0 = blockIdx.z * 64;
  for (int e = threadIdx.x; e < 4096; e += 256) {
    int p = e >> 6, d = e & 63;
    tile[p][d] = (_Float16)pv[((size_t)(b * SP_ + p0 + p) * H_ + h) * HD_ + dd0 + d];
  }
  __syncthreads();
  for (int e = threadIdx.x; e < 4096; e += 256) {
    int d = e >> 6, p = e & 63;
    Vt[((size_t)bh * HD_ + dd0 + d) * L_ + p0 + p] = tile[p][d];
  }
}

// ============ GEMM-8phase: 256x256 tile, BK=64, 8 waves + fused epilogue ====
// K-loop identical to R3 (validated). Epilogue: acc -> LDS tile [256][264]
// (pair-packed b32 writes), then cooperative RoPE (Q/K) or transpose (V)
// writes straight to Qh / Kc[SP:] / Vt[:,SP:]. qkvh buffer eliminated.
__global__ __launch_bounds__(512, 2) void k_gemm8(const _Float16* __restrict__ A,
                                                  const _Float16* __restrict__ Bw,
                                                  const float2* __restrict__ cs,
                                                  _Float16* __restrict__ Qh,
                                                  _Float16* __restrict__ Kc,
                                                  _Float16* __restrict__ Vt,
                                                  int K, int nbn) {
  __shared__ _Float16 SH[256 * 264];            // 132 KB; pipeline uses first 128 KB
  const int tid = threadIdx.x, w = tid >> 6, lane = tid & 63;
  const int r = lane & 15, g = lane >> 4;
  const int wr = w >> 2, wc = w & 3;
  const int xg = g ^ ((r >> 1) & 3);
  const int nwg = gridDim.x, flat = blockIdx.x, cpx = nwg >> 3;
  const int swz = (flat & 7) * cpx + (flat >> 3);
  const int m0 = (swz / nbn) * 256, n0 = (swz % nbn) * 256;
  const int NT = K >> 6;

  _Float16* const LAp = SH;                     // 4 x 8192
  _Float16* const LBp = SH + 32768;             // 4 x 8192

  // stage half-tile hidx: tile=hidx>>2, kind: 0=A_k0,1=B_k0,2=A_k1,3=B_k1
  auto stage = [&](int hidx) {
    if (hidx >= 4 * NT) return;
    int Ts = hidx >> 2, kind = hidx & 3;
    int kk = kind >> 1, isB = kind & 1;
    const _Float16* src = isB ? Bw : A;
    int rb = isB ? n0 : m0;
    _Float16* slot = (isB ? LBp : LAp) + ((Ts & 1) * 2 + kk) * 8192;
    int kt = (Ts << 6) + (kk << 5);
#pragma unroll
    for (int j = 0; j < 2; j++) {
      int chunk = j * 8 + w;
      int gi = chunk * 64 + lane;
      int row = gi >> 2;
      int cg = (gi & 3) ^ ((gi >> 3) & 3);
      gload16(src + (size_t)(rb + row) * K + kt + cg * 8,
              slot + (size_t)chunk * 512);
    }
  };

  f32x4 acc[8][4] = {};
  f16x8 af[8], bf0, bf1;

  // prologue: halves 0..6
#pragma unroll
  for (int h = 0; h < 7; h++) stage(h);
  asm volatile("s_waitcnt vmcnt(6)" ::: "memory");
  BARRIER;

  for (int T = 0; T < NT; ++T) {
    const int d = (T & 1) * 2;
    const _Float16* la0 = LAp + d * 8192;
    const _Float16* lb0 = LBp + d * 8192;
    const _Float16* la1 = LAp + (d + 1) * 8192;
    const _Float16* lb1 = LBp + (d + 1) * 8192;
    // ---- phase 1 ----
#pragma unroll
    for (int mf = 0; mf < 8; mf++)
      af[mf] = *(const f16x8*)(la0 + (wr * 128 + mf * 16 + r) * 32 + xg * 8);
    bf0 = *(const f16x8*)(lb0 + (wc * 64 + r) * 32 + xg * 8);
    bf1 = *(const f16x8*)(lb0 + (wc * 64 + 16 + r) * 32 + xg * 8);
    stage(4 * T + 7);
    BARRIER;
    __builtin_amdgcn_s_setprio(1);
#pragma unroll
    for (int mf = 0; mf < 8; mf++) acc[mf][0] = MFMA16(af[mf], bf0, acc[mf][0]);
#pragma unroll
    for (int mf = 0; mf < 8; mf++) acc[mf][1] = MFMA16(af[mf], bf1, acc[mf][1]);
    __builtin_amdgcn_s_setprio(0);
    BARRIER;
    // ---- phase 2 ----
    bf0 = *(const f16x8*)(lb0 + (wc * 64 + 32 + r) * 32 + xg * 8);
    bf1 = *(const f16x8*)(lb0 + (wc * 64 + 48 + r) * 32 + xg * 8);
    stage(4 * T + 8);
    BARRIER;
    __builtin_amdgcn_s_setprio(1);
#pragma unroll
    for (int mf = 0; mf < 8; mf++) acc[mf][2] = MFMA16(af[mf], bf0, acc[mf][2]);
#pragma unroll
    for (int mf = 0; mf < 8; mf++) acc[mf][3] = MFMA16(af[mf], bf1, acc[mf][3]);
    __builtin_amdgcn_s_setprio(0);
    BARRIER;
    // ---- phase 3 ----
#pragma unroll
    for (int mf = 0; mf < 8; mf++)
      af[mf] = *(const f16x8*)(la1 + (wr * 128 + mf * 16 + r) * 32 + xg * 8);
    bf0 = *(const f16x8*)(lb1 + (wc * 64 + r) * 32 + xg * 8);
    bf1 = *(const f16x8*)(lb1 + (wc * 64 + 16 + r) * 32 + xg * 8);
    stage(4 * T + 9);
    BARRIER;
    __builtin_amdgcn_s_setprio(1);
#pragma unroll
    for (int mf = 0; mf < 8; mf++) acc[mf][0] = MFMA16(af[mf], bf0, acc[mf][0]);
#pragma unroll
    for (int mf = 0; mf < 8; mf++) acc[mf][1] = MFMA16(af[mf], bf1, acc[mf][1]);
    __builtin_amdgcn_s_setprio(0);
    BARRIER;
    // ---- phase 4 ----
    bf0 = *(const f16x8*)(lb1 + (wc * 64 + 32 + r) * 32 + xg * 8);
    bf1 = *(const f16x8*)(lb1 + (wc * 64 + 48 + r) * 32 + xg * 8);
    stage(4 * T + 10);
    BARRIER;
    __builtin_amdgcn_s_setprio(1);
#pragma unroll
    for (int mf = 0; mf < 8; mf++) acc[mf][2] = MFMA16(af[mf], bf0, acc[mf][2]);
#pragma unroll
    for (int mf = 0; mf < 8; mf++) acc[mf][3] = MFMA16(af[mf], bf1, acc[mf][3]);
    __builtin_amdgcn_s_setprio(0);
    if (T < NT - 2) asm volatile("s_waitcnt vmcnt(6)" ::: "memory");
    else            asm volatile("s_waitcnt vmcnt(0)" ::: "memory");
    BARRIER;
  }

  // ===== fused epilogue =====
  // (a) acc -> LDS CT[256][264], pair-packed b32 stores (even-r lanes)
#pragma unroll
  for (int mf = 0; mf < 8; mf++)
#pragma unroll
    for (int nf = 0; nf < 4; nf++)
#pragma unroll
      for (int q = 0; q < 4; q++) {
        float v = acc[mf][nf][q];
        float vp = __shfl_xor(v, 1);
        if (!(r & 1)) {
          int row = wr * 128 + mf * 16 + g * 4 + q;
          int col = wc * 64 + nf * 16 + r;
          f16x2 pk2; pk2[0] = (_Float16)v; pk2[1] = (_Float16)vp;
          *(f16x2*)&SH[row * 264 + col] = pk2;
        }
      }
  __syncthreads();

  // (b) cooperative write-out
  const int seg = n0 >> 11;                    // 0=Q, 1=K, 2=V
  const int h0 = (n0 >> 7) & 15;
  const int bq = m0 >> 10, ib = m0 & 1023;
  if (seg < 2) {
#pragma unroll
    for (int cc = 0; cc < 16; cc++) {
      int cid = cc * 512 + tid;
      int row = cid >> 5, colc = (cid & 31) * 8;
      f16x8 v = *(const f16x8*)&SH[row * 264 + colc];
      int i = ib + row;
      int h = h0 + (colc >> 7), dd = colc & 127;
      const float2* cp = cs + (size_t)i * 128 + dd;
      f16x8 o;
#pragma unroll
      for (int j = 0; j < 4; j++) {
        float e  = (float)v[2 * j], od = (float)v[2 * j + 1];
        float2 c0 = cp[2 * j], c1 = cp[2 * j + 1];
        float e2 = e * c0.x - od * c0.y;
        float o2 = od * c1.x + e * c1.y;
        if (seg == 0) { e2 *= SCALE_; o2 *= SCALE_; }
        o[2 * j] = (_Float16)e2; o[2 * j + 1] = (_Float16)o2;
      }
      if (seg == 0)
        *(f16x8*)(Qh + ((size_t)(bq * H_ + h) * S_ + i) * HD_ + dd) = o;
      else
        *(f16x8*)(Kc + ((size_t)(bq * H_ + h) * L_ + SP_ + i) * HD_ + dd) = o;
    }
  } else {
#pragma unroll
    for (int cc = 0; cc < 16; cc++) {
      int cid = cc * 512 + tid;
      int dcol = cid & 255, i8 = cid >> 8;
      int i0 = i8 * 8;
      f16x8 v;
#pragma unroll
      for (int k = 0; k < 8; k++) v[k] = SH[(i0 + k) * 264 + dcol];
      int h = h0 + (dcol >> 7), dd = dcol & 127;
      *(f16x8*)(Vt + ((size_t)(bq * H_ + h) * HD_ + dd) * L_ + SP_ + ib + i0) = v;
    }
  }
}

// ---------------- GEMM (m97 structure, conflict-free LDS) — out-proj --------
template<bool F16OUT>
__global__ __launch_bounds__(256) void k_gemm(const _Float16* __restrict__ A,
                                              const _Float16* __restrict__ Bw,
                                              void* __restrict__ Cout,
                                              int M, int N, int K) {
  __shared__ _Float16 As[128 * 32];
  __shared__ _Float16 Bs[128 * 32];
  const int tid = threadIdx.x, w = tid >> 6, lane = tid & 63;
  const int r = lane & 15, g = lane >> 4;
  const int m0 = blockIdx.y * 128, n0 = blockIdx.x * 128;
  const int wm = (w >> 1) * 64, wn = (w & 1) * 64;
  f32x4 acc[4][4] = {};
  for (int kt = 0; kt < K; kt += 32) {
#pragma unroll
    for (int it = 0; it < 2; it++) {
      int bg = it * 256 + w * 64;
      int gi = bg + lane;
      int row = ((gi >> 5) << 3) + (gi & 7);
      int cg = (gi >> 3) & 3;
      gload16(A  + (size_t)(m0 + row) * K + kt + cg * 8, &As[bg * 8]);
      gload16(Bw + (size_t)(n0 + row) * K + kt + cg * 8, &Bs[bg * 8]);
    }
    __syncthreads();
    f16x8 af[4], bf[4];
#pragma unroll
    for (int i = 0; i < 4; i++) {
      af[i] = *(const f16x8*)&As[gstore(wm + i * 16 + r, g) * 8];
      bf[i] = *(const f16x8*)&Bs[gstore(wn + i * 16 + r, g) * 8];
    }
#pragma unroll
    for (int i = 0; i < 4; i++)
#pragma unroll
      for (int j = 0; j < 4; j++)
        acc[i][j] = MFMA16(af[i], bf[j], acc[i][j]);
    __syncthreads();
  }
#pragma unroll
  for (int i = 0; i < 4; i++)
#pragma unroll
    for (int j = 0; j < 4; j++)
#pragma unroll
      for (int q = 0; q < 4; q++) {
        size_t idx = (size_t)(m0 + wm + i * 16 + g * 4 + q) * N + n0 + wn + j * 16 + r;
        if constexpr (F16OUT) ((_Float16*)Cout)[idx] = (_Float16)acc[i][j][q];
        else                  ((float*)Cout)[idx]    = acc[i][j][q];
      }
}

// ---------------- Flash attention (unchanged) ----------------
__global__ __launch_bounds__(256) void k_attn(const _Float16* __restrict__ Qh,
                                              const _Float16* __restrict__ Kc,
                                              const _Float16* __restrict__ Vt,
                                              _Float16* __restrict__ Oh) {
  __shared__ _Float16 Kl[64 * 128];
  __shared__ _Float16 Vl[128 * 64];
  __shared__ _Float16 Pl[4][16 * 64];
  const int tid = threadIdx.x, w = tid >> 6, lane = tid & 63;
  const int r = lane & 15, g = lane >> 4;
  const int bh = blockIdx.x, tile = blockIdx.y;
  const int i0 = tile * 64, q0 = i0 + w * 16;
  const _Float16* Kbase = Kc + (size_t)bh * L_ * HD_;
  const _Float16* Vbase = Vt + (size_t)bh * HD_ * L_;
  f16x8 qf[4];
  {
    const _Float16* qp = Qh + ((size_t)bh * S_ + q0 + r) * HD_ + g * 8;
#pragma unroll
    for (int kk = 0; kk < 4; kk++) qf[kk] = *(const f16x8*)(qp + kk * 32);
  }
  f32x4 acc[8] = {};
  float mrun = -1e30f, lrun = 0.f;
  const int lim = SP_ + q0 + r;
  const int nch = (SP_ + i0 + 64) >> 6;
  for (int c = 0; c < nch; c++) {
    const int c0 = c << 6;
#pragma unroll
    for (int it = 0; it < 4; it++) {
      int bg = it * 256 + w * 64;
      int gr = bg + lane;
      int krow = gr >> 4, kc = ((gr & 15) ^ (krow & 7)) * 8;
      gload16(Kbase + (size_t)(c0 + krow) * HD_ + kc, &Kl[bg * 8]);
      int vrow = gr >> 3, vc = ((gr & 7) ^ (vrow & 7)) * 8;
      gload16(Vbase + (size_t)vrow * L_ + c0 + vc, &Vl[bg * 8]);
    }
    __syncthreads();
    f32x4 sc[4] = {};
#pragma unroll
    for (int mf = 0; mf < 4; mf++)
#pragma unroll
      for (int kk = 0; kk < 4; kk++) {
        int row = mf * 16 + r;
        int gran = (g + kk * 4) ^ (row & 7);
        f16x8 kf = *(const f16x8*)&Kl[row * 128 + gran * 8];
        sc[mf] = MFMA16(kf, qf[kk], sc[mf]);
      }
    float p[4][4];
    float rmax = -1e30f;
#pragma unroll
    for (int mf = 0; mf < 4; mf++)
#pragma unroll
      for (int jj = 0; jj < 4; jj++) {
        float v = sc[mf][jj];
        int kp = c0 + mf * 16 + g * 4 + jj;
        if (kp > lim) v = -1e30f;
        p[mf][jj] = v;
        rmax = fmaxf(rmax, v);
      }
    rmax = fmaxf(rmax, __shfl_xor(rmax, 16));
    rmax = fmaxf(rmax, __shfl_xor(rmax, 32));
    float mnew = fmaxf(mrun, rmax);
    float scale = __expf(mrun - mnew);
    float psum = 0.f;
#pragma unroll
    for (int mf = 0; mf < 4; mf++)
#pragma unroll
      for (int jj = 0; jj < 4; jj++) {
        float e = __expf(p[mf][jj] - mnew);
        p[mf][jj] = e;
        psum += e;
      }
    psum += __shfl_xor(psum, 16);
    psum += __shfl_xor(psum, 32);
    lrun = lrun * scale + psum;
    mrun = mnew;
#pragma unroll
    for (int mf = 0; mf < 4; mf++) {
      f16x4 ph;
#pragma unroll
      for (int jj = 0; jj < 4; jj++) ph[jj] = (_Float16)p[mf][jj];
      int g16 = (mf * 2 + (g >> 1)) ^ (r & 7);
      *(f16x4*)&Pl[w][r * 64 + g16 * 8 + (g & 1) * 4] = ph;
    }
    float scj[4];
#pragma unroll
    for (int jj = 0; jj < 4; jj++) scj[jj] = __shfl(scale, g * 4 + jj);
#pragma unroll
    for (int nf = 0; nf < 8; nf++)
#pragma unroll
      for (int jj = 0; jj < 4; jj++) acc[nf][jj] *= scj[jj];
#pragma unroll
    for (int kk = 0; kk < 2; kk++) {
      f16x8 pf = *(const f16x8*)&Pl[w][r * 64 + ((g + kk * 4) ^ (r & 7)) * 8];
#pragma unroll
      for (int nf = 0; nf < 8; nf++) {
        int vrow = nf * 16 + r;
        int gran = (g + kk * 4) ^ (vrow & 7);
        f16x8 vf = *(const f16x8*)&Vl[vrow * 64 + gran * 8];
        acc[nf] = MFMA16(pf, vf, acc[nf]);
      }
    }
    __syncthreads();
  }
  float inv[4];
#pragma unroll
  for (int jj = 0; jj < 4; jj++) inv[jj] = 1.f / __shfl(lrun, g * 4 + jj);
  const int b = bh >> 4, h = bh & 15;
#pragma unroll
  for (int nf = 0; nf < 8; nf++)
#pragma unroll
    for (int jj = 0; jj < 4; jj++) {
      size_t idx = (size_t)(b * S_ + i0 + w * 16 + g * 4 + jj) * E_ + h * HD_ + nf * 16 + r;
      Oh[idx] = (_Float16)(acc[nf][jj] * inv[jj]);
    }
}

extern "C" void kernel_launch(void* const* d_in, const int* in_sizes, int n_in,
                              void* d_out, int out_size, void* d_ws, size_t ws_size,
                              hipStream_t stream) {
  (void)in_sizes; (void)n_in; (void)out_size; (void)ws_size;
  const float* x    = (const float*)d_in[0];
  const float* Wqkv = (const float*)d_in[1];
  const float* Wout = (const float*)d_in[2];
  const float* pk   = (const float*)d_in[3];
  const float* pv   = (const float*)d_in[4];

  char* ws = (char*)d_ws;
  _Float16* Xh   = (_Float16*)(ws);               // 8.39MB (reused as Oh)
  _Float16* Wh   = (_Float16*)(ws + 8388608);     // 25.2MB
  _Float16* Qhb  = (_Float16*)(ws + 33554432);    // 8.39MB
  _Float16* Kcb  = (_Float16*)(ws + 41943040);    // 16.8MB
  _Float16* Vtb  = (_Float16*)(ws + 58720256);    // 16.8MB
  float2*   cs   = (float2*)  (ws + 75497472);    // 1MB
  _Float16* Woh  = (_Float16*)(ws + 76546048);    // 8.39MB  (total ~85MB)
  _Float16* Ohb  = Xh;

  k_cvtall<<<10240, 256, 0, stream>>>(x, Wqkv, Wout, Xh, Wh, Woh);
  k_cstab <<<512,   256, 0, stream>>>(cs);
  k_pastk <<<2048,  256, 0, stream>>>(pk, Kcb);
  k_pastv <<<dim3(32, 16, 2), 256, 0, stream>>>(pv, Vtb);
  k_gemm8 <<<192, 512, 0, stream>>>(Xh, Wh, cs, Qhb, Kcb, Vtb, E_, 24);
  k_attn  <<<dim3(32, 16), 256, 0, stream>>>(Qhb, Kcb, Vtb, Ohb);
  k_gemm<false><<<dim3(16, 16), 256, 0, stream>>>(Ohb, Woh, d_out, M_, E_, E_);
}